// Round 2
// baseline (5520.843 us; speedup 1.0000x reference)
//
#include <hip/hip_runtime.h>

// k-means cluster step: N=400000 points, D=256, K=50 (fp32).
// out[0:12800]    = per-cluster sums (50x256, fp32)
// out[12800:12850]= per-cluster counts (as fp32 values)
//
// Structure: 8 points per wave, 8 lanes per point. Each lane holds 8 float4
// chunks of its point's row in REGISTERS (all indices compile-time static --
// any runtime index would demote to scratch, which was round 0's 438MB
// WRITE_SIZE disaster). Dot products vs all 50 centroids accumulate in
// acc[50] (static, fully unrolled). 3-step quad... octet butterfly gives all
// 8 lanes the full dot product bitwise-identically, so argmin is consistent.
// Scatter into a padded LDS accumulator with LDS atomics; per-block partials
// to d_ws; tiny second kernel reduces 768 partials.

constexpr int K = 50;
constexpr int D = 256;
constexpr int SROW = D + 1;       // 257: padded LDS row stride (bank spread)
constexpr int OUT_N = K * D + K;  // 12850
constexpr int GRID = 768;         // 3 blocks/CU x 256 CU

__global__ void kmeans_assign(const float* __restrict__ x,
                              const float* __restrict__ c,
                              float* __restrict__ partial,
                              float* __restrict__ out,
                              int N, int useAtomic) {
    __shared__ float s_sums[K * SROW];
    __shared__ float s_c2[K];
    __shared__ int   s_cnt[K];

    const int tid = threadIdx.x;
    for (int idx = tid; idx < K * SROW; idx += 256) s_sums[idx] = 0.f;
    if (tid < K) {
        s_cnt[tid] = 0;
        float s = 0.f;
        const float4* cr = (const float4*)(c + tid * D);
        for (int i = 0; i < D / 4; ++i) {
            float4 v = cr[i];
            s += v.x * v.x + v.y * v.y + v.z * v.z + v.w * v.w;
        }
        s_c2[tid] = s;
    }
    __syncthreads();

    const int lane = tid & 63;
    const int o    = lane & 7;    // chunk owner: owns float4 chunks o, 8+o? no: 8 chunks stride-8
    const int g    = lane >> 3;   // point index within group of 8
    const int waveId  = (blockIdx.x * 256 + tid) >> 6;
    const int nWaves  = gridDim.x * 4;
    const int nGroups = (N + 7) >> 3;

    for (int pg = waveId; pg < nGroups; pg += nWaves) {
        const int p = pg * 8 + g;
        const bool valid = (p < N);
        const float* xb = x + (size_t)p * D;

        // Lane (o) owns elements d in [32*i + 4*o, 32*i + 4*o + 4), i=0..7.
        // Per load instr (fixed i): 8 points x contiguous 128B -> coalesced.
        float4 xr0, xr1, xr2, xr3, xr4, xr5, xr6, xr7;
        {
            const float4 z{0.f, 0.f, 0.f, 0.f};
            xr0 = valid ? *(const float4*)(xb + 32 * 0 + 4 * o) : z;
            xr1 = valid ? *(const float4*)(xb + 32 * 1 + 4 * o) : z;
            xr2 = valid ? *(const float4*)(xb + 32 * 2 + 4 * o) : z;
            xr3 = valid ? *(const float4*)(xb + 32 * 3 + 4 * o) : z;
            xr4 = valid ? *(const float4*)(xb + 32 * 4 + 4 * o) : z;
            xr5 = valid ? *(const float4*)(xb + 32 * 5 + 4 * o) : z;
            xr6 = valid ? *(const float4*)(xb + 32 * 6 + 4 * o) : z;
            xr7 = valid ? *(const float4*)(xb + 32 * 7 + 4 * o) : z;
        }

        float acc[K];
        #pragma unroll
        for (int k = 0; k < K; ++k) acc[k] = 0.f;

        // i outer / k inner: 50 independent FMA chains interleave -> no
        // latency stalls. Everything fully unrolled (static indices).
        #pragma unroll
        for (int i = 0; i < 8; ++i) {
            float4 xv;
            switch (i) {  // compile-time resolved under full unroll
                case 0: xv = xr0; break; case 1: xv = xr1; break;
                case 2: xv = xr2; break; case 3: xv = xr3; break;
                case 4: xv = xr4; break; case 5: xv = xr5; break;
                case 6: xv = xr6; break; default: xv = xr7; break;
            }
            const float* cb = c + 32 * i + 4 * o;
            #pragma unroll
            for (int k = 0; k < K; ++k) {
                const float4 cv = *(const float4*)(cb + (size_t)k * D);
                acc[k] = fmaf(xv.x, cv.x, acc[k]);
                acc[k] = fmaf(xv.y, cv.y, acc[k]);
                acc[k] = fmaf(xv.z, cv.z, acc[k]);
                acc[k] = fmaf(xv.w, cv.w, acc[k]);
            }
        }

        // octet butterfly: all 8 lanes of a point get the identical full dot
        #pragma unroll
        for (int k = 0; k < K; ++k) {
            float v = acc[k];
            v += __shfl_xor(v, 1, 64);
            v += __shfl_xor(v, 2, 64);
            v += __shfl_xor(v, 4, 64);
            acc[k] = v;
        }

        // argmin of c2 - 2*dot (same ordering as ref d2); first-min tie-break
        int best = 0;
        float bs = s_c2[0] - 2.f * acc[0];
        #pragma unroll
        for (int k = 1; k < K; ++k) {
            float s = s_c2[k] - 2.f * acc[k];
            if (s < bs) { bs = s; best = k; }
        }

        if (valid) {
            if (o == 0) atomicAdd(&s_cnt[best], 1);
            // bank = (best + 4o + j) % 32 within fixed i: 8 owners spread
            float* row = &s_sums[best * SROW + 4 * o];
            atomicAdd(&row[32 * 0 + 0], xr0.x); atomicAdd(&row[32 * 0 + 1], xr0.y);
            atomicAdd(&row[32 * 0 + 2], xr0.z); atomicAdd(&row[32 * 0 + 3], xr0.w);
            atomicAdd(&row[32 * 1 + 0], xr1.x); atomicAdd(&row[32 * 1 + 1], xr1.y);
            atomicAdd(&row[32 * 1 + 2], xr1.z); atomicAdd(&row[32 * 1 + 3], xr1.w);
            atomicAdd(&row[32 * 2 + 0], xr2.x); atomicAdd(&row[32 * 2 + 1], xr2.y);
            atomicAdd(&row[32 * 2 + 2], xr2.z); atomicAdd(&row[32 * 2 + 3], xr2.w);
            atomicAdd(&row[32 * 3 + 0], xr3.x); atomicAdd(&row[32 * 3 + 1], xr3.y);
            atomicAdd(&row[32 * 3 + 2], xr3.z); atomicAdd(&row[32 * 3 + 3], xr3.w);
            atomicAdd(&row[32 * 4 + 0], xr4.x); atomicAdd(&row[32 * 4 + 1], xr4.y);
            atomicAdd(&row[32 * 4 + 2], xr4.z); atomicAdd(&row[32 * 4 + 3], xr4.w);
            atomicAdd(&row[32 * 5 + 0], xr5.x); atomicAdd(&row[32 * 5 + 1], xr5.y);
            atomicAdd(&row[32 * 5 + 2], xr5.z); atomicAdd(&row[32 * 5 + 3], xr5.w);
            atomicAdd(&row[32 * 6 + 0], xr6.x); atomicAdd(&row[32 * 6 + 1], xr6.y);
            atomicAdd(&row[32 * 6 + 2], xr6.z); atomicAdd(&row[32 * 6 + 3], xr6.w);
            atomicAdd(&row[32 * 7 + 0], xr7.x); atomicAdd(&row[32 * 7 + 1], xr7.y);
            atomicAdd(&row[32 * 7 + 2], xr7.z); atomicAdd(&row[32 * 7 + 3], xr7.w);
        }
    }
    __syncthreads();

    if (useAtomic) {
        for (int idx = tid; idx < K * D; idx += 256) {
            int k = idx >> 8, d = idx & 255;
            atomicAdd(&out[idx], s_sums[k * SROW + d]);
        }
        for (int k2 = tid; k2 < K; k2 += 256)
            atomicAdd(&out[K * D + k2], (float)s_cnt[k2]);
    } else {
        float* pb = partial + (size_t)blockIdx.x * OUT_N;
        for (int idx = tid; idx < K * D; idx += 256) {
            int k = idx >> 8, d = idx & 255;
            pb[idx] = s_sums[k * SROW + d];
        }
        for (int k2 = tid; k2 < K; k2 += 256)
            pb[K * D + k2] = (float)s_cnt[k2];
    }
}

__global__ void kmeans_reduce(const float* __restrict__ partial,
                              float* __restrict__ out, int G) {
    int j = blockIdx.x * blockDim.x + threadIdx.x;
    if (j >= OUT_N) return;
    float s = 0.f;
    for (int b = 0; b < G; ++b) s += partial[(size_t)b * OUT_N + j];
    out[j] = s;
}

extern "C" void kernel_launch(void* const* d_in, const int* in_sizes, int n_in,
                              void* d_out, int out_size, void* d_ws, size_t ws_size,
                              hipStream_t stream) {
    const float* x = (const float*)d_in[0];
    const float* c = (const float*)d_in[1];
    float* out = (float*)d_out;
    const int N = in_sizes[0] / D;

    const size_t need = (size_t)GRID * OUT_N * sizeof(float);
    const int useAtomic = (ws_size < need) ? 1 : 0;

    if (useAtomic) {
        hipMemsetAsync(d_out, 0, (size_t)out_size * sizeof(float), stream);
    }
    kmeans_assign<<<GRID, 256, 0, stream>>>(x, c, (float*)d_ws, out, N, useAtomic);
    if (!useAtomic) {
        kmeans_reduce<<<(OUT_N + 255) / 256, 256, 0, stream>>>(
            (const float*)d_ws, out, GRID);
    }
}

// Round 3
// 5173.761 us; speedup vs baseline: 1.0671x; 1.0671x over previous
//
#include <hip/hip_runtime.h>

// k-means cluster step: N=400000 points, D=256, K=50 (fp32).
// out[0:12800]    = per-cluster sums (50x256, fp32)
// out[12800:12850]= per-cluster counts (as fp32 values)
//
// Structure: 8 points per wave, 8 lanes per point. Each lane holds 8 float4
// chunks of its point's row in REGISTERS (all indices compile-time static).
// Dot products vs all 50 centroids accumulate in acc[50] (static, fully
// unrolled, i-outer/k-inner so 50 FMA chains interleave).
//
// __launch_bounds__(256,3) is LOAD-BEARING: without it hipcc caps VGPRs at 64
// and spills acc[50] to scratch (round 2: 12.4 GB HBM traffic, 5348 us).
// 3 waves/EU -> 168-VGPR budget; need ~130; LDS (52KB -> 3 blocks/CU) is the
// occupancy limiter either way.

constexpr int K = 50;
constexpr int D = 256;
constexpr int SROW = D + 1;       // 257: padded LDS row stride (bank spread)
constexpr int OUT_N = K * D + K;  // 12850
constexpr int GRID = 768;         // 3 blocks/CU x 256 CU

__global__ __launch_bounds__(256, 3)
void kmeans_assign(const float* __restrict__ x,
                   const float* __restrict__ c,
                   float* __restrict__ partial,
                   float* __restrict__ out,
                   int N, int useAtomic) {
    __shared__ float s_sums[K * SROW];
    __shared__ float s_c2[K];
    __shared__ int   s_cnt[K];

    const int tid = threadIdx.x;
    for (int idx = tid; idx < K * SROW; idx += 256) s_sums[idx] = 0.f;
    if (tid < K) {
        s_cnt[tid] = 0;
        float s = 0.f;
        const float4* cr = (const float4*)(c + tid * D);
        for (int i = 0; i < D / 4; ++i) {
            float4 v = cr[i];
            s += v.x * v.x + v.y * v.y + v.z * v.z + v.w * v.w;
        }
        s_c2[tid] = s;
    }
    __syncthreads();

    const int lane = tid & 63;
    const int o    = lane & 7;    // chunk owner within point
    const int g    = lane >> 3;   // point index within group of 8
    const int waveId  = (blockIdx.x * 256 + tid) >> 6;
    const int nWaves  = gridDim.x * 4;
    const int nGroups = (N + 7) >> 3;

    for (int pg = waveId; pg < nGroups; pg += nWaves) {
        const int p = pg * 8 + g;
        const bool valid = (p < N);
        const float* xb = x + (size_t)p * D;

        // Lane (o) owns elements d in [32*i + 4*o, 32*i + 4*o + 4), i=0..7.
        // Per load instr (fixed i): 8 points x contiguous 128B -> coalesced.
        float4 xr0, xr1, xr2, xr3, xr4, xr5, xr6, xr7;
        {
            const float4 z{0.f, 0.f, 0.f, 0.f};
            xr0 = valid ? *(const float4*)(xb + 32 * 0 + 4 * o) : z;
            xr1 = valid ? *(const float4*)(xb + 32 * 1 + 4 * o) : z;
            xr2 = valid ? *(const float4*)(xb + 32 * 2 + 4 * o) : z;
            xr3 = valid ? *(const float4*)(xb + 32 * 3 + 4 * o) : z;
            xr4 = valid ? *(const float4*)(xb + 32 * 4 + 4 * o) : z;
            xr5 = valid ? *(const float4*)(xb + 32 * 5 + 4 * o) : z;
            xr6 = valid ? *(const float4*)(xb + 32 * 6 + 4 * o) : z;
            xr7 = valid ? *(const float4*)(xb + 32 * 7 + 4 * o) : z;
        }

        float acc[K];
        #pragma unroll
        for (int k = 0; k < K; ++k) acc[k] = 0.f;

        #pragma unroll
        for (int i = 0; i < 8; ++i) {
            float4 xv;
            switch (i) {  // compile-time resolved under full unroll
                case 0: xv = xr0; break; case 1: xv = xr1; break;
                case 2: xv = xr2; break; case 3: xv = xr3; break;
                case 4: xv = xr4; break; case 5: xv = xr5; break;
                case 6: xv = xr6; break; default: xv = xr7; break;
            }
            const float* cb = c + 32 * i + 4 * o;
            #pragma unroll
            for (int k = 0; k < K; ++k) {
                const float4 cv = *(const float4*)(cb + (size_t)k * D);
                acc[k] = fmaf(xv.x, cv.x, acc[k]);
                acc[k] = fmaf(xv.y, cv.y, acc[k]);
                acc[k] = fmaf(xv.z, cv.z, acc[k]);
                acc[k] = fmaf(xv.w, cv.w, acc[k]);
            }
        }

        // octet butterfly: all 8 lanes of a point get the identical full dot
        #pragma unroll
        for (int k = 0; k < K; ++k) {
            float v = acc[k];
            v += __shfl_xor(v, 1, 64);
            v += __shfl_xor(v, 2, 64);
            v += __shfl_xor(v, 4, 64);
            acc[k] = v;
        }

        // argmin of c2 - 2*dot (same ordering as ref d2); first-min tie-break
        int best = 0;
        float bs = s_c2[0] - 2.f * acc[0];
        #pragma unroll
        for (int k = 1; k < K; ++k) {
            float s = s_c2[k] - 2.f * acc[k];
            if (s < bs) { bs = s; best = k; }
        }

        if (valid) {
            if (o == 0) atomicAdd(&s_cnt[best], 1);
            // bank = (best + 4o + j) % 32 (257*best mod 32 == best mod 32)
            float* row = &s_sums[best * SROW + 4 * o];
            atomicAdd(&row[32 * 0 + 0], xr0.x); atomicAdd(&row[32 * 0 + 1], xr0.y);
            atomicAdd(&row[32 * 0 + 2], xr0.z); atomicAdd(&row[32 * 0 + 3], xr0.w);
            atomicAdd(&row[32 * 1 + 0], xr1.x); atomicAdd(&row[32 * 1 + 1], xr1.y);
            atomicAdd(&row[32 * 1 + 2], xr1.z); atomicAdd(&row[32 * 1 + 3], xr1.w);
            atomicAdd(&row[32 * 2 + 0], xr2.x); atomicAdd(&row[32 * 2 + 1], xr2.y);
            atomicAdd(&row[32 * 2 + 2], xr2.z); atomicAdd(&row[32 * 2 + 3], xr2.w);
            atomicAdd(&row[32 * 3 + 0], xr3.x); atomicAdd(&row[32 * 3 + 1], xr3.y);
            atomicAdd(&row[32 * 3 + 2], xr3.z); atomicAdd(&row[32 * 3 + 3], xr3.w);
            atomicAdd(&row[32 * 4 + 0], xr4.x); atomicAdd(&row[32 * 4 + 1], xr4.y);
            atomicAdd(&row[32 * 4 + 2], xr4.z); atomicAdd(&row[32 * 4 + 3], xr4.w);
            atomicAdd(&row[32 * 5 + 0], xr5.x); atomicAdd(&row[32 * 5 + 1], xr5.y);
            atomicAdd(&row[32 * 5 + 2], xr5.z); atomicAdd(&row[32 * 5 + 3], xr5.w);
            atomicAdd(&row[32 * 6 + 0], xr6.x); atomicAdd(&row[32 * 6 + 1], xr6.y);
            atomicAdd(&row[32 * 6 + 2], xr6.z); atomicAdd(&row[32 * 6 + 3], xr6.w);
            atomicAdd(&row[32 * 7 + 0], xr7.x); atomicAdd(&row[32 * 7 + 1], xr7.y);
            atomicAdd(&row[32 * 7 + 2], xr7.z); atomicAdd(&row[32 * 7 + 3], xr7.w);
        }
    }
    __syncthreads();

    if (useAtomic) {
        for (int idx = tid; idx < K * D; idx += 256) {
            int k = idx >> 8, d = idx & 255;
            atomicAdd(&out[idx], s_sums[k * SROW + d]);
        }
        for (int k2 = tid; k2 < K; k2 += 256)
            atomicAdd(&out[K * D + k2], (float)s_cnt[k2]);
    } else {
        float* pb = partial + (size_t)blockIdx.x * OUT_N;
        for (int idx = tid; idx < K * D; idx += 256) {
            int k = idx >> 8, d = idx & 255;
            pb[idx] = s_sums[k * SROW + d];
        }
        for (int k2 = tid; k2 < K; k2 += 256)
            pb[K * D + k2] = (float)s_cnt[k2];
    }
}

__global__ void kmeans_reduce(const float* __restrict__ partial,
                              float* __restrict__ out, int G) {
    int j = blockIdx.x * blockDim.x + threadIdx.x;
    if (j >= OUT_N) return;
    float s = 0.f;
    for (int b = 0; b < G; ++b) s += partial[(size_t)b * OUT_N + j];
    out[j] = s;
}

extern "C" void kernel_launch(void* const* d_in, const int* in_sizes, int n_in,
                              void* d_out, int out_size, void* d_ws, size_t ws_size,
                              hipStream_t stream) {
    const float* x = (const float*)d_in[0];
    const float* c = (const float*)d_in[1];
    float* out = (float*)d_out;
    const int N = in_sizes[0] / D;

    const size_t need = (size_t)GRID * OUT_N * sizeof(float);
    const int useAtomic = (ws_size < need) ? 1 : 0;

    if (useAtomic) {
        hipMemsetAsync(d_out, 0, (size_t)out_size * sizeof(float), stream);
    }
    kmeans_assign<<<GRID, 256, 0, stream>>>(x, c, (float*)d_ws, out, N, useAtomic);
    if (!useAtomic) {
        kmeans_reduce<<<(OUT_N + 255) / 256, 256, 0, stream>>>(
            (const float*)d_ws, out, GRID);
    }
}

// Round 4
// 1247.276 us; speedup vs baseline: 4.4263x; 4.1480x over previous
//
#include <hip/hip_runtime.h>

// k-means cluster step: N=400000 points, D=256, K=50 (fp32).
// out[0:12800]    = per-cluster sums (50x256, fp32)
// out[12800:12850]= per-cluster counts (as fp32 values)
//
// Structure: 8 points per wave, 8 lanes per point. Each lane holds 8 float4
// chunks of its point's row in REGISTERS (all indices compile-time static).
// K processed in 2 chunks of 25 (bounds worst-case register pressure ~100).
//
// amdgpu_waves_per_eu(3,3) is LOAD-BEARING: round 3 showed __launch_bounds__
// (256,3) alone lets the allocator target 6 waves/EU (VGPR=84) and spill
// acc[] to scratch (10.4 GB HBM fetch, 5000 us). max=3 tells regalloc that
// occupancy beyond 3 waves/EU is worthless (LDS 52KB caps at 3 blocks/CU
// anyway), unlocking the full 168-VGPR budget.

constexpr int K = 50;
constexpr int KC = 25;            // k-chunk size
constexpr int D = 256;
constexpr int SROW = D + 1;       // 257: padded LDS row stride (bank spread)
constexpr int OUT_N = K * D + K;  // 12850
constexpr int GRID = 768;         // 3 blocks/CU x 256 CU

__global__
__attribute__((amdgpu_flat_work_group_size(256, 256), amdgpu_waves_per_eu(3, 3)))
void kmeans_assign(const float* __restrict__ x,
                   const float* __restrict__ c,
                   float* __restrict__ partial,
                   float* __restrict__ out,
                   int N, int useAtomic) {
    __shared__ float s_sums[K * SROW];
    __shared__ float s_c2[K];
    __shared__ int   s_cnt[K];

    const int tid = threadIdx.x;
    for (int idx = tid; idx < K * SROW; idx += 256) s_sums[idx] = 0.f;
    if (tid < K) {
        s_cnt[tid] = 0;
        float s = 0.f;
        const float4* cr = (const float4*)(c + tid * D);
        for (int i = 0; i < D / 4; ++i) {
            float4 v = cr[i];
            s += v.x * v.x + v.y * v.y + v.z * v.z + v.w * v.w;
        }
        s_c2[tid] = s;
    }
    __syncthreads();

    const int lane = tid & 63;
    const int o    = lane & 7;    // chunk owner within point
    const int g    = lane >> 3;   // point index within group of 8
    const int waveId  = (blockIdx.x * 256 + tid) >> 6;
    const int nWaves  = gridDim.x * 4;
    const int nGroups = (N + 7) >> 3;

    for (int pg = waveId; pg < nGroups; pg += nWaves) {
        const int p = pg * 8 + g;
        const bool valid = (p < N);
        const float* xb = x + (size_t)p * D;

        // Lane (o) owns elements d in [32*i + 4*o, 32*i + 4*o + 4), i=0..7.
        // Per load instr (fixed i): 8 points x contiguous 128B -> coalesced.
        float4 xr0, xr1, xr2, xr3, xr4, xr5, xr6, xr7;
        {
            const float4 z{0.f, 0.f, 0.f, 0.f};
            xr0 = valid ? *(const float4*)(xb + 32 * 0 + 4 * o) : z;
            xr1 = valid ? *(const float4*)(xb + 32 * 1 + 4 * o) : z;
            xr2 = valid ? *(const float4*)(xb + 32 * 2 + 4 * o) : z;
            xr3 = valid ? *(const float4*)(xb + 32 * 3 + 4 * o) : z;
            xr4 = valid ? *(const float4*)(xb + 32 * 4 + 4 * o) : z;
            xr5 = valid ? *(const float4*)(xb + 32 * 5 + 4 * o) : z;
            xr6 = valid ? *(const float4*)(xb + 32 * 6 + 4 * o) : z;
            xr7 = valid ? *(const float4*)(xb + 32 * 7 + 4 * o) : z;
        }

        int   best = 0;
        float bs   = 3.4e38f;

        // Two k-chunks of 25: acc live-set is 25, not 50.
        #pragma unroll 1
        for (int kc = 0; kc < 2; ++kc) {
            const int k0 = kc * KC;

            float acc[KC];
            #pragma unroll
            for (int k = 0; k < KC; ++k) acc[k] = 0.f;

            #pragma unroll
            for (int i = 0; i < 8; ++i) {
                float4 xv;
                switch (i) {  // compile-time resolved under full unroll
                    case 0: xv = xr0; break; case 1: xv = xr1; break;
                    case 2: xv = xr2; break; case 3: xv = xr3; break;
                    case 4: xv = xr4; break; case 5: xv = xr5; break;
                    case 6: xv = xr6; break; default: xv = xr7; break;
                }
                const float* cb = c + (size_t)k0 * D + 32 * i + 4 * o;
                #pragma unroll
                for (int k = 0; k < KC; ++k) {
                    const float4 cv = *(const float4*)(cb + (size_t)k * D);
                    acc[k] = fmaf(xv.x, cv.x, acc[k]);
                    acc[k] = fmaf(xv.y, cv.y, acc[k]);
                    acc[k] = fmaf(xv.z, cv.z, acc[k]);
                    acc[k] = fmaf(xv.w, cv.w, acc[k]);
                }
            }

            // octet butterfly: all 8 lanes of a point get identical full dots
            #pragma unroll
            for (int k = 0; k < KC; ++k) {
                float v = acc[k];
                v += __shfl_xor(v, 1, 64);
                v += __shfl_xor(v, 2, 64);
                v += __shfl_xor(v, 4, 64);
                acc[k] = v;
            }

            // fold into running argmin (increasing k + strict < = first-min
            // tie-break, matching jnp.argmin)
            #pragma unroll
            for (int k = 0; k < KC; ++k) {
                float s = s_c2[k0 + k] - 2.f * acc[k];
                if (s < bs) { bs = s; best = k0 + k; }
            }
        }

        if (valid) {
            if (o == 0) atomicAdd(&s_cnt[best], 1);
            // bank = (best + 4o + j) % 32 (257*best mod 32 == best mod 32)
            float* row = &s_sums[best * SROW + 4 * o];
            atomicAdd(&row[32 * 0 + 0], xr0.x); atomicAdd(&row[32 * 0 + 1], xr0.y);
            atomicAdd(&row[32 * 0 + 2], xr0.z); atomicAdd(&row[32 * 0 + 3], xr0.w);
            atomicAdd(&row[32 * 1 + 0], xr1.x); atomicAdd(&row[32 * 1 + 1], xr1.y);
            atomicAdd(&row[32 * 1 + 2], xr1.z); atomicAdd(&row[32 * 1 + 3], xr1.w);
            atomicAdd(&row[32 * 2 + 0], xr2.x); atomicAdd(&row[32 * 2 + 1], xr2.y);
            atomicAdd(&row[32 * 2 + 2], xr2.z); atomicAdd(&row[32 * 2 + 3], xr2.w);
            atomicAdd(&row[32 * 3 + 0], xr3.x); atomicAdd(&row[32 * 3 + 1], xr3.y);
            atomicAdd(&row[32 * 3 + 2], xr3.z); atomicAdd(&row[32 * 3 + 3], xr3.w);
            atomicAdd(&row[32 * 4 + 0], xr4.x); atomicAdd(&row[32 * 4 + 1], xr4.y);
            atomicAdd(&row[32 * 4 + 2], xr4.z); atomicAdd(&row[32 * 4 + 3], xr4.w);
            atomicAdd(&row[32 * 5 + 0], xr5.x); atomicAdd(&row[32 * 5 + 1], xr5.y);
            atomicAdd(&row[32 * 5 + 2], xr5.z); atomicAdd(&row[32 * 5 + 3], xr5.w);
            atomicAdd(&row[32 * 6 + 0], xr6.x); atomicAdd(&row[32 * 6 + 1], xr6.y);
            atomicAdd(&row[32 * 6 + 2], xr6.z); atomicAdd(&row[32 * 6 + 3], xr6.w);
            atomicAdd(&row[32 * 7 + 0], xr7.x); atomicAdd(&row[32 * 7 + 1], xr7.y);
            atomicAdd(&row[32 * 7 + 2], xr7.z); atomicAdd(&row[32 * 7 + 3], xr7.w);
        }
    }
    __syncthreads();

    if (useAtomic) {
        for (int idx = tid; idx < K * D; idx += 256) {
            int k = idx >> 8, d = idx & 255;
            atomicAdd(&out[idx], s_sums[k * SROW + d]);
        }
        for (int k2 = tid; k2 < K; k2 += 256)
            atomicAdd(&out[K * D + k2], (float)s_cnt[k2]);
    } else {
        float* pb = partial + (size_t)blockIdx.x * OUT_N;
        for (int idx = tid; idx < K * D; idx += 256) {
            int k = idx >> 8, d = idx & 255;
            pb[idx] = s_sums[k * SROW + d];
        }
        for (int k2 = tid; k2 < K; k2 += 256)
            pb[K * D + k2] = (float)s_cnt[k2];
    }
}

__global__ void kmeans_reduce(const float* __restrict__ partial,
                              float* __restrict__ out, int G) {
    int j = blockIdx.x * blockDim.x + threadIdx.x;
    if (j >= OUT_N) return;
    float s = 0.f;
    for (int b = 0; b < G; ++b) s += partial[(size_t)b * OUT_N + j];
    out[j] = s;
}

extern "C" void kernel_launch(void* const* d_in, const int* in_sizes, int n_in,
                              void* d_out, int out_size, void* d_ws, size_t ws_size,
                              hipStream_t stream) {
    const float* x = (const float*)d_in[0];
    const float* c = (const float*)d_in[1];
    float* out = (float*)d_out;
    const int N = in_sizes[0] / D;

    const size_t need = (size_t)GRID * OUT_N * sizeof(float);
    const int useAtomic = (ws_size < need) ? 1 : 0;

    if (useAtomic) {
        hipMemsetAsync(d_out, 0, (size_t)out_size * sizeof(float), stream);
    }
    kmeans_assign<<<GRID, 256, 0, stream>>>(x, c, (float*)d_ws, out, N, useAtomic);
    if (!useAtomic) {
        kmeans_reduce<<<(OUT_N + 255) / 256, 256, 0, stream>>>(
            (const float*)d_ws, out, GRID);
    }
}

// Round 5
// 776.952 us; speedup vs baseline: 7.1058x; 1.6053x over previous
//
#include <hip/hip_runtime.h>

// k-means cluster step: N=400000, D=256, K=50 (fp32 in/out).
// scores = X·C^T via mfma_f32_16x16x32_f16 (f16 inputs, fp32 accum).
// Per wave: 16 points x 64 padded centroid cols; C staged in LDS as f16.
// argmin via C/D layout (col=lane&15, row=(lane>>4)*4+reg) + 16-lane
// butterfly with index tie-break; scatter the f16 A-frags into padded LDS
// sums with ds atomics; per-block partials -> d_ws -> tiny reduce kernel.

typedef _Float16 f16x8 __attribute__((ext_vector_type(8)));
typedef float    f32x4 __attribute__((ext_vector_type(4)));

constexpr int K    = 50;
constexpr int KP   = 64;    // padded centroid count (4 n-tiles of 16)
constexpr int D    = 256;
constexpr int CST  = 264;   // f16 LDS row stride: 528B = 33*16 (aligned, 4-bank/row shift)
constexpr int SROW = 257;   // padded fp32 sums stride
constexpr int OUT_N = K * D + K;  // 12850
constexpr int BLK  = 1024;
constexpr int GRID = 256;   // 1 block/CU (LDS ~86KB), 16 waves/CU

__global__ __launch_bounds__(BLK)
void kmeans_mfma(const float* __restrict__ x, const float* __restrict__ c,
                 float* __restrict__ partial, float* __restrict__ out,
                 int N, int useAtomic) {
    __shared__ _Float16 s_C[KP * CST];   // 33792 B
    __shared__ float    s_sums[K * SROW];// 51400 B
    __shared__ float    s_c2[KP];
    __shared__ int      s_cnt[K];

    const int tid = threadIdx.x;
    for (int i = tid; i < KP * CST; i += BLK) s_C[i] = (_Float16)0.f;
    for (int i = tid; i < K * SROW; i += BLK) s_sums[i] = 0.f;
    if (tid < K) s_cnt[tid] = 0;
    __syncthreads();
    for (int i = tid; i < K * D; i += BLK) {
        int row = i >> 8, col = i & 255;
        s_C[row * CST + col] = (_Float16)c[i];
    }
    if (tid < KP) {
        float s = 0.f;
        if (tid < K) {
            const float4* cr = (const float4*)(c + tid * D);
            for (int i = 0; i < D / 4; ++i) {
                float4 v = cr[i];
                s += v.x * v.x + v.y * v.y + v.z * v.z + v.w * v.w;
            }
        }
        s_c2[tid] = s;
    }
    __syncthreads();

    const int lane = tid & 63;
    const int ci   = lane & 15;  // A: x-row within tile; D: column index
    const int g    = lane >> 4;  // k-chunk / point-subgroup
    const int wave = blockIdx.x * (BLK / 64) + (tid >> 6);
    const int nWaves = gridDim.x * (BLK / 64);
    const int nTiles = (N + 15) >> 4;

    // loop-invariant c2 (or +inf mask) for this lane's 4 columns
    const float INF = 3.4e38f;
    float c2v0 = (ci      < K) ? s_c2[ci]      : INF;
    float c2v1 = (16 + ci < K) ? s_c2[16 + ci] : INF;
    float c2v2 = (32 + ci < K) ? s_c2[32 + ci] : INF;
    float c2v3 = (48 + ci < K) ? s_c2[48 + ci] : INF;

    const _Float16* cb = &s_C[ci * CST + g * 8];

    for (int t = wave; t < nTiles; t += nWaves) {
        const int row = t * 16 + ci;
        const bool rv = row < N;
        const float* xb = x + (size_t)row * D;
        const float4 z4{0.f, 0.f, 0.f, 0.f};

        // A-frags: lane holds x[row][ks*32 + g*8 .. +8] as f16 (also the
        // scatter payload). Per instr: 16 rows x 4x16B chunks -> coalesced.
        f16x8 a0, a1, a2, a3, a4, a5, a6, a7;
#define LOADA(i) { \
        float4 u = rv ? *(const float4*)(xb + 32 * i + 8 * g)     : z4; \
        float4 v = rv ? *(const float4*)(xb + 32 * i + 8 * g + 4) : z4; \
        a##i = (f16x8){(_Float16)u.x, (_Float16)u.y, (_Float16)u.z, (_Float16)u.w, \
                       (_Float16)v.x, (_Float16)v.y, (_Float16)v.z, (_Float16)v.w}; }
        LOADA(0) LOADA(1) LOADA(2) LOADA(3) LOADA(4) LOADA(5) LOADA(6) LOADA(7)
#undef LOADA

        f32x4 acc0{0,0,0,0}, acc1{0,0,0,0}, acc2{0,0,0,0}, acc3{0,0,0,0};
        // B-frag: lane = centroid row (nt*16+ci), k-chunk g -> dense b128,
        // ~2-way banks (CST=264). D = A(points x K) * B(K x centroids).
#define STEP(nt, ks) { \
        f16x8 b = *(const f16x8*)(cb + nt * 16 * CST + 32 * ks); \
        acc##nt = __builtin_amdgcn_mfma_f32_16x16x32_f16(a##ks, b, acc##nt, 0, 0, 0); }
        STEP(0,0) STEP(0,1) STEP(0,2) STEP(0,3) STEP(0,4) STEP(0,5) STEP(0,6) STEP(0,7)
        STEP(1,0) STEP(1,1) STEP(1,2) STEP(1,3) STEP(1,4) STEP(1,5) STEP(1,6) STEP(1,7)
        STEP(2,0) STEP(2,1) STEP(2,2) STEP(2,3) STEP(2,4) STEP(2,5) STEP(2,6) STEP(2,7)
        STEP(3,0) STEP(3,1) STEP(3,2) STEP(3,3) STEP(3,4) STEP(3,5) STEP(3,6) STEP(3,7)
#undef STEP

        // argmin per point-row r (point p = 4*g + r): local over 4 cols,
        // then 16-lane butterfly with first-min (smallest k) tie-break.
        int b0, b1, b2, b3;
#define ARGMIN(r, OUTB) { \
        float m = c2v0 - 2.f * acc0[r]; int bi = ci; \
        { float s = c2v1 - 2.f * acc1[r]; if (s < m) { m = s; bi = 16 + ci; } } \
        { float s = c2v2 - 2.f * acc2[r]; if (s < m) { m = s; bi = 32 + ci; } } \
        { float s = c2v3 - 2.f * acc3[r]; if (s < m) { m = s; bi = 48 + ci; } } \
        { float pm; int pb; \
          pm = __shfl_xor(m, 1, 64); pb = __shfl_xor(bi, 1, 64); \
          if (pm < m || (pm == m && pb < bi)) { m = pm; bi = pb; } \
          pm = __shfl_xor(m, 2, 64); pb = __shfl_xor(bi, 2, 64); \
          if (pm < m || (pm == m && pb < bi)) { m = pm; bi = pb; } \
          pm = __shfl_xor(m, 4, 64); pb = __shfl_xor(bi, 4, 64); \
          if (pm < m || (pm == m && pb < bi)) { m = pm; bi = pb; } \
          pm = __shfl_xor(m, 8, 64); pb = __shfl_xor(bi, 8, 64); \
          if (pm < m || (pm == m && pb < bi)) { m = pm; bi = pb; } } \
        OUTB = bi; }
        ARGMIN(0, b0) ARGMIN(1, b1) ARGMIN(2, b2) ARGMIN(3, b3)
#undef ARGMIN

        // counts: lane (g, ci<4) owns point 4*g + ci
        if (ci < 4) {
            int pb2 = (ci == 0) ? b0 : (ci == 1) ? b1 : (ci == 2) ? b2 : b3;
            if (t * 16 + 4 * g + ci < N) atomicAdd(&s_cnt[pb2], 1);
        }

        // route best[point ci] to this lane: held by lane group (ci>>2)
        const int src = (ci >> 2) << 4;
        int q0 = __shfl(b0, src, 64);
        int q1 = __shfl(b1, src, 64);
        int q2 = __shfl(b2, src, 64);
        int q3 = __shfl(b3, src, 64);
        const int rr = ci & 3;
        const int dest = (rr == 0) ? q0 : (rr == 1) ? q1 : (rr == 2) ? q2 : q3;

        // scatter: lane adds its A-frag (row ci) into s_sums[dest]
        if (rv) {
            float* sr = &s_sums[dest * SROW + g * 8];
#define SCAT(i) { \
            atomicAdd(&sr[32 * i + 0], (float)a##i[0]); \
            atomicAdd(&sr[32 * i + 1], (float)a##i[1]); \
            atomicAdd(&sr[32 * i + 2], (float)a##i[2]); \
            atomicAdd(&sr[32 * i + 3], (float)a##i[3]); \
            atomicAdd(&sr[32 * i + 4], (float)a##i[4]); \
            atomicAdd(&sr[32 * i + 5], (float)a##i[5]); \
            atomicAdd(&sr[32 * i + 6], (float)a##i[6]); \
            atomicAdd(&sr[32 * i + 7], (float)a##i[7]); }
            SCAT(0) SCAT(1) SCAT(2) SCAT(3) SCAT(4) SCAT(5) SCAT(6) SCAT(7)
#undef SCAT
        }
    }
    __syncthreads();

    if (useAtomic) {
        for (int idx = tid; idx < K * D; idx += BLK) {
            int k = idx >> 8, d = idx & 255;
            atomicAdd(&out[idx], s_sums[k * SROW + d]);
        }
        for (int k2 = tid; k2 < K; k2 += BLK)
            atomicAdd(&out[K * D + k2], (float)s_cnt[k2]);
    } else {
        float* pb = partial + (size_t)blockIdx.x * OUT_N;
        for (int idx = tid; idx < K * D; idx += BLK) {
            int k = idx >> 8, d = idx & 255;
            pb[idx] = s_sums[k * SROW + d];
        }
        for (int k2 = tid; k2 < K; k2 += BLK)
            pb[K * D + k2] = (float)s_cnt[k2];
    }
}

__global__ void kmeans_reduce(const float* __restrict__ partial,
                              float* __restrict__ out, int G) {
    int j = blockIdx.x * blockDim.x + threadIdx.x;
    if (j >= OUT_N) return;
    float s = 0.f;
    for (int b = 0; b < G; ++b) s += partial[(size_t)b * OUT_N + j];
    out[j] = s;
}

extern "C" void kernel_launch(void* const* d_in, const int* in_sizes, int n_in,
                              void* d_out, int out_size, void* d_ws, size_t ws_size,
                              hipStream_t stream) {
    const float* x = (const float*)d_in[0];
    const float* c = (const float*)d_in[1];
    float* out = (float*)d_out;
    const int N = in_sizes[0] / D;

    const size_t need = (size_t)GRID * OUT_N * sizeof(float);
    const int useAtomic = (ws_size < need) ? 1 : 0;

    if (useAtomic) {
        hipMemsetAsync(d_out, 0, (size_t)out_size * sizeof(float), stream);
    }
    kmeans_mfma<<<GRID, BLK, 0, stream>>>(x, c, (float*)d_ws, out, N, useAtomic);
    if (!useAtomic) {
        kmeans_reduce<<<(OUT_N + 255) / 256, 256, 0, stream>>>(
            (const float*)d_ws, out, GRID);
    }
}

// Round 6
// 775.705 us; speedup vs baseline: 7.1172x; 1.0016x over previous
//
#include <hip/hip_runtime.h>

// k-means cluster step: N=400000, D=256, K=50 (fp32 in/out).
// scores = X·C^T via mfma_f32_16x16x32_f16 (f16 inputs, fp32 accum).
// Per wave: 16 points x 64 padded centroid cols; C staged in LDS as f16.
// argmin via C/D layout (col=lane&15, row=(lane>>4)*4+reg) + 16-lane
// butterfly with index tie-break; scatter the f16 A-frags into padded LDS
// sums with ds atomics; per-block partials -> d_ws -> tiny reduce kernel.
//
// amdgpu_waves_per_eu(4,4) is LOAD-BEARING (rounds 2/3/5 all lost 4-7x to
// this): LDS=86KB forces 1 block/CU = exactly 4 waves/EU, but without the
// pin the allocator targets higher occupancy, caps VGPR at 64, and spills
// the a-frags/acc to scratch (round 5: 131MB scratch writes, VALUBusy 2.6%).
// 4 waves/EU -> 128-VGPR budget; need ~100.

typedef _Float16 f16x8 __attribute__((ext_vector_type(8)));
typedef float    f32x4 __attribute__((ext_vector_type(4)));

constexpr int K    = 50;
constexpr int KP   = 64;    // padded centroid count (4 n-tiles of 16)
constexpr int D    = 256;
constexpr int CST  = 264;   // f16 LDS row stride: 528B = 33*16 (aligned, 4-bank/row shift)
constexpr int SROW = 257;   // padded fp32 sums stride
constexpr int OUT_N = K * D + K;  // 12850
constexpr int BLK  = 1024;
constexpr int GRID = 256;   // 1 block/CU (LDS ~86KB), 16 waves/CU

__global__
__attribute__((amdgpu_flat_work_group_size(BLK, BLK), amdgpu_waves_per_eu(4, 4)))
void kmeans_mfma(const float* __restrict__ x, const float* __restrict__ c,
                 float* __restrict__ partial, float* __restrict__ out,
                 int N, int useAtomic) {
    __shared__ _Float16 s_C[KP * CST];   // 33792 B
    __shared__ float    s_sums[K * SROW];// 51400 B
    __shared__ float    s_c2[KP];
    __shared__ int      s_cnt[K];

    const int tid = threadIdx.x;
    for (int i = tid; i < KP * CST; i += BLK) s_C[i] = (_Float16)0.f;
    for (int i = tid; i < K * SROW; i += BLK) s_sums[i] = 0.f;
    if (tid < K) s_cnt[tid] = 0;
    __syncthreads();
    for (int i = tid; i < K * D; i += BLK) {
        int row = i >> 8, col = i & 255;
        s_C[row * CST + col] = (_Float16)c[i];
    }
    if (tid < KP) {
        float s = 0.f;
        if (tid < K) {
            const float4* cr = (const float4*)(c + tid * D);
            for (int i = 0; i < D / 4; ++i) {
                float4 v = cr[i];
                s += v.x * v.x + v.y * v.y + v.z * v.z + v.w * v.w;
            }
        }
        s_c2[tid] = s;
    }
    __syncthreads();

    const int lane = tid & 63;
    const int ci   = lane & 15;  // A: x-row within tile; D: column index
    const int g    = lane >> 4;  // k-chunk / point-subgroup
    const int wave = blockIdx.x * (BLK / 64) + (tid >> 6);
    const int nWaves = gridDim.x * (BLK / 64);
    const int nTiles = (N + 15) >> 4;

    // loop-invariant c2 (or +inf mask) for this lane's 4 columns
    const float INF = 3.4e38f;
    float c2v0 = (ci      < K) ? s_c2[ci]      : INF;
    float c2v1 = (16 + ci < K) ? s_c2[16 + ci] : INF;
    float c2v2 = (32 + ci < K) ? s_c2[32 + ci] : INF;
    float c2v3 = (48 + ci < K) ? s_c2[48 + ci] : INF;

    const _Float16* cb = &s_C[ci * CST + g * 8];

    for (int t = wave; t < nTiles; t += nWaves) {
        const int row = t * 16 + ci;
        const bool rv = row < N;
        const float* xb = x + (size_t)row * D;
        const float4 z4{0.f, 0.f, 0.f, 0.f};

        // A-frags: lane holds x[row][ks*32 + g*8 .. +8] as f16 (also the
        // scatter payload). Per instr: 16 rows x 4x16B chunks -> coalesced.
        f16x8 a0, a1, a2, a3, a4, a5, a6, a7;
#define LOADA(i) { \
        float4 u = rv ? *(const float4*)(xb + 32 * i + 8 * g)     : z4; \
        float4 v = rv ? *(const float4*)(xb + 32 * i + 8 * g + 4) : z4; \
        a##i = (f16x8){(_Float16)u.x, (_Float16)u.y, (_Float16)u.z, (_Float16)u.w, \
                       (_Float16)v.x, (_Float16)v.y, (_Float16)v.z, (_Float16)v.w}; }
        LOADA(0) LOADA(1) LOADA(2) LOADA(3) LOADA(4) LOADA(5) LOADA(6) LOADA(7)
#undef LOADA

        f32x4 acc0{0,0,0,0}, acc1{0,0,0,0}, acc2{0,0,0,0}, acc3{0,0,0,0};
        // B-frag: lane = centroid row (nt*16+ci), k-chunk g -> dense b128,
        // ~2-way banks (CST=264). D = A(points x K) * B(K x centroids).
#define STEP(nt, ks) { \
        f16x8 b = *(const f16x8*)(cb + nt * 16 * CST + 32 * ks); \
        acc##nt = __builtin_amdgcn_mfma_f32_16x16x32_f16(a##ks, b, acc##nt, 0, 0, 0); }
        STEP(0,0) STEP(0,1) STEP(0,2) STEP(0,3) STEP(0,4) STEP(0,5) STEP(0,6) STEP(0,7)
        STEP(1,0) STEP(1,1) STEP(1,2) STEP(1,3) STEP(1,4) STEP(1,5) STEP(1,6) STEP(1,7)
        STEP(2,0) STEP(2,1) STEP(2,2) STEP(2,3) STEP(2,4) STEP(2,5) STEP(2,6) STEP(2,7)
        STEP(3,0) STEP(3,1) STEP(3,2) STEP(3,3) STEP(3,4) STEP(3,5) STEP(3,6) STEP(3,7)
#undef STEP

        // argmin per point-row r (point p = 4*g + r): local over 4 cols,
        // then 16-lane butterfly with first-min (smallest k) tie-break.
        int b0, b1, b2, b3;
#define ARGMIN(r, OUTB) { \
        float m = c2v0 - 2.f * acc0[r]; int bi = ci; \
        { float s = c2v1 - 2.f * acc1[r]; if (s < m) { m = s; bi = 16 + ci; } } \
        { float s = c2v2 - 2.f * acc2[r]; if (s < m) { m = s; bi = 32 + ci; } } \
        { float s = c2v3 - 2.f * acc3[r]; if (s < m) { m = s; bi = 48 + ci; } } \
        { float pm; int pb; \
          pm = __shfl_xor(m, 1, 64); pb = __shfl_xor(bi, 1, 64); \
          if (pm < m || (pm == m && pb < bi)) { m = pm; bi = pb; } \
          pm = __shfl_xor(m, 2, 64); pb = __shfl_xor(bi, 2, 64); \
          if (pm < m || (pm == m && pb < bi)) { m = pm; bi = pb; } \
          pm = __shfl_xor(m, 4, 64); pb = __shfl_xor(bi, 4, 64); \
          if (pm < m || (pm == m && pb < bi)) { m = pm; bi = pb; } \
          pm = __shfl_xor(m, 8, 64); pb = __shfl_xor(bi, 8, 64); \
          if (pm < m || (pm == m && pb < bi)) { m = pm; bi = pb; } } \
        OUTB = bi; }
        ARGMIN(0, b0) ARGMIN(1, b1) ARGMIN(2, b2) ARGMIN(3, b3)
#undef ARGMIN

        // counts: lane (g, ci<4) owns point 4*g + ci
        if (ci < 4) {
            int pb2 = (ci == 0) ? b0 : (ci == 1) ? b1 : (ci == 2) ? b2 : b3;
            if (t * 16 + 4 * g + ci < N) atomicAdd(&s_cnt[pb2], 1);
        }

        // route best[point ci] to this lane: held by lane group (ci>>2)
        const int src = (ci >> 2) << 4;
        int q0 = __shfl(b0, src, 64);
        int q1 = __shfl(b1, src, 64);
        int q2 = __shfl(b2, src, 64);
        int q3 = __shfl(b3, src, 64);
        const int rr = ci & 3;
        const int dest = (rr == 0) ? q0 : (rr == 1) ? q1 : (rr == 2) ? q2 : q3;

        // scatter: lane adds its A-frag (row ci) into s_sums[dest]
        if (rv) {
            float* sr = &s_sums[dest * SROW + g * 8];
#define SCAT(i) { \
            atomicAdd(&sr[32 * i + 0], (float)a##i[0]); \
            atomicAdd(&sr[32 * i + 1], (float)a##i[1]); \
            atomicAdd(&sr[32 * i + 2], (float)a##i[2]); \
            atomicAdd(&sr[32 * i + 3], (float)a##i[3]); \
            atomicAdd(&sr[32 * i + 4], (float)a##i[4]); \
            atomicAdd(&sr[32 * i + 5], (float)a##i[5]); \
            atomicAdd(&sr[32 * i + 6], (float)a##i[6]); \
            atomicAdd(&sr[32 * i + 7], (float)a##i[7]); }
            SCAT(0) SCAT(1) SCAT(2) SCAT(3) SCAT(4) SCAT(5) SCAT(6) SCAT(7)
#undef SCAT
        }
    }
    __syncthreads();

    if (useAtomic) {
        for (int idx = tid; idx < K * D; idx += BLK) {
            int k = idx >> 8, d = idx & 255;
            atomicAdd(&out[idx], s_sums[k * SROW + d]);
        }
        for (int k2 = tid; k2 < K; k2 += BLK)
            atomicAdd(&out[K * D + k2], (float)s_cnt[k2]);
    } else {
        float* pb = partial + (size_t)blockIdx.x * OUT_N;
        for (int idx = tid; idx < K * D; idx += BLK) {
            int k = idx >> 8, d = idx & 255;
            pb[idx] = s_sums[k * SROW + d];
        }
        for (int k2 = tid; k2 < K; k2 += BLK)
            pb[K * D + k2] = (float)s_cnt[k2];
    }
}

__global__ void kmeans_reduce(const float* __restrict__ partial,
                              float* __restrict__ out, int G) {
    int j = blockIdx.x * blockDim.x + threadIdx.x;
    if (j >= OUT_N) return;
    float s = 0.f;
    for (int b = 0; b < G; ++b) s += partial[(size_t)b * OUT_N + j];
    out[j] = s;
}

extern "C" void kernel_launch(void* const* d_in, const int* in_sizes, int n_in,
                              void* d_out, int out_size, void* d_ws, size_t ws_size,
                              hipStream_t stream) {
    const float* x = (const float*)d_in[0];
    const float* c = (const float*)d_in[1];
    float* out = (float*)d_out;
    const int N = in_sizes[0] / D;

    const size_t need = (size_t)GRID * OUT_N * sizeof(float);
    const int useAtomic = (ws_size < need) ? 1 : 0;

    if (useAtomic) {
        hipMemsetAsync(d_out, 0, (size_t)out_size * sizeof(float), stream);
    }
    kmeans_mfma<<<GRID, BLK, 0, stream>>>(x, c, (float*)d_ws, out, N, useAtomic);
    if (!useAtomic) {
        kmeans_reduce<<<(OUT_N + 255) / 256, 256, 0, stream>>>(
            (const float*)d_ws, out, GRID);
    }
}